// Round 1
// baseline (246.105 us; speedup 1.0000x reference)
//
#include <hip/hip_runtime.h>
#include <cstdint>

#define LRELU_ALPHA 0.2f
#define NEG_INF -9000000000000000.0f
#define L2E 1.4426950408889634f

typedef __bf16 bf16x8 __attribute__((ext_vector_type(8)));
typedef unsigned short ushortx8 __attribute__((ext_vector_type(8)));
typedef float floatx4 __attribute__((ext_vector_type(4)));

constexpr int Bb = 8, Nn = 2048, Ff = 64;
constexpr int TJ = 64;            // j-tile width
constexpr int LSTR = 72;          // LDS row stride in bf16 (16B-aligned, padded vs 64)

__device__ __forceinline__ unsigned short f2bf(float f) {
    unsigned u = __builtin_bit_cast(unsigned, f);
    u = u + 0x7FFFu + ((u >> 16) & 1u);   // round-to-nearest-even
    return (unsigned short)(u >> 16);
}

// ---------------- Kernel 1: h = x@W (fp32), s1 = h.a1, s2 = h.a2, hT (bf16, transposed) ----
__global__ __launch_bounds__(256) void gat_prep(
    const float* __restrict__ x, const float* __restrict__ W, const float* __restrict__ a,
    unsigned short* __restrict__ hT, float* __restrict__ s1g, float* __restrict__ s2g)
{
    __shared__ unsigned short hblk[64 * LSTR];   // [f][i_local] bf16, padded stride
    const int tid = threadIdx.x;
    const int blk = blockIdx.x;            // 256 blocks: 32 row-blocks x 8 batches
    const int b  = blk >> 5;
    const int i0 = (blk & 31) * 64;
    const int w    = tid >> 6;
    const int lane = tid & 63;             // lane = output feature f

    // W column for this lane, held in VGPRs (reused across 16 rows)
    float wcol[64];
    #pragma unroll
    for (int k = 0; k < 64; ++k) wcol[k] = W[k * 64 + lane];
    const float a1 = a[lane], a2 = a[64 + lane];

    for (int r = 0; r < 16; ++r) {
        const int il = w * 16 + r;
        const int i  = i0 + il;
        const float* xrow = x + ((size_t)(b * Nn + i)) * 64;   // wave-uniform -> s_loads
        float h = 0.f;
        #pragma unroll
        for (int k = 0; k < 64; ++k) h = fmaf(xrow[k], wcol[k], h);
        float p1 = h * a1, p2 = h * a2;
        #pragma unroll
        for (int off = 32; off; off >>= 1) {
            p1 += __shfl_xor(p1, off);
            p2 += __shfl_xor(p2, off);
        }
        if (lane == 0) { s1g[b * Nn + i] = p1; s2g[b * Nn + i] = p2; }
        hblk[lane * LSTR + il] = f2bf(h);          // transpose via LDS
    }
    __syncthreads();
    // write hT[b][f][i0..i0+63]: thread t -> f = t>>2, 16-elem chunk (t&3)
    {
        const int f = tid >> 2, c = (tid & 3) * 16;
        const uint4* src = reinterpret_cast<const uint4*>(&hblk[f * LSTR + c]);
        uint4 v0 = src[0], v1 = src[1];
        uint4* dst = reinterpret_cast<uint4*>(hT + ((size_t)b * 64 + f) * Nn + i0 + c);
        dst[0] = v0; dst[1] = v1;
    }
}

// ---------------- Kernel 2: fused masked-softmax attention + PV + ELU (flash-style) --------
// Block = 128 threads (2 waves), TI = 32 rows/block. Wave w owns rows i0+w*16+(lane&15).
// e-compute lane mapping == MFMA A-fragment layout: m = lane&15, k = (lane>>4)*8 + jj.
__global__ __launch_bounds__(128) void gat_attn(
    const int* __restrict__ adj, const unsigned short* __restrict__ hT,
    const float* __restrict__ s1g, const float* __restrict__ s2g,
    float* __restrict__ out)
{
    __shared__ unsigned short hT_lds[64 * LSTR];   // [f][j] bf16 tile, padded
    __shared__ float s2_lds[TJ];

    const int tid  = threadIdx.x;
    const int blk  = blockIdx.x;          // 512 blocks
    const int gr0  = blk * 32;
    const int b    = gr0 >> 11;
    const int i0   = gr0 & 2047;
    const int w    = tid >> 6;
    const int lane = tid & 63;
    const int fl   = lane & 15;           // A-row (i) in e-phase; B-col (f) in mfma phase
    const int q    = lane >> 4;           // quad id: k-group selector

    const int i = i0 + w * 16 + fl;       // this lane's score row
    const float s1v = s1g[b * Nn + i];
    const int* adj_row = adj + ((size_t)(b * Nn + i)) * Nn;
    const unsigned short* hTb = hT + (size_t)b * 64 * Nn;
    const float* s2b = s2g + b * Nn;

    float m = NEG_INF, l = 0.f;
    floatx4 C[4] = {};                    // 4 f-tiles of 16x16 C

    // staging assignment: thread -> f-row sf, 32-col chunk sc
    const int sf = tid >> 1, sc = (tid & 1) * 32;

    // prefetch adj tile 0 (16 ints = rows' j-window [0,64) split by quad)
    int4 adjv[4];
    {
        const int4* ap0 = reinterpret_cast<const int4*>(adj_row + q * 8);
        adjv[0] = ap0[0]; adjv[1] = ap0[1];
        const int4* ap1 = reinterpret_cast<const int4*>(adj_row + 32 + q * 8);
        adjv[2] = ap1[0]; adjv[3] = ap1[1];
    }

    for (int jt = 0; jt < Nn / TJ; ++jt) {
        const int j0 = jt * TJ;
        __syncthreads();
        // stage hT tile [64 f][64 j] -> LDS (padded), + s2 tile
        {
            const uint4* gsrc = reinterpret_cast<const uint4*>(hTb + (size_t)sf * Nn + j0 + sc);
            uint4 g0 = gsrc[0], g1 = gsrc[1], g2 = gsrc[2], g3 = gsrc[3];
            uint4* ldst = reinterpret_cast<uint4*>(&hT_lds[sf * LSTR + sc]);
            ldst[0] = g0; ldst[1] = g1; ldst[2] = g2; ldst[3] = g3;
            if (tid < TJ) s2_lds[tid] = s2b[j0 + tid];
        }
        __syncthreads();

        // prefetch next adj tile into regs (overlaps with compute below)
        int4 nadj[4] = {};
        if (jt + 1 < Nn / TJ) {
            const int* nrow = adj_row + j0 + TJ;
            const int4* ap0 = reinterpret_cast<const int4*>(nrow + q * 8);
            nadj[0] = ap0[0]; nadj[1] = ap0[1];
            const int4* ap1 = reinterpret_cast<const int4*>(nrow + 32 + q * 8);
            nadj[2] = ap1[0]; nadj[3] = ap1[1];
        }

        // scores: e[t*8+jj] for j = j0 + t*32 + q*8 + jj
        float e[16];
        const int* av = reinterpret_cast<const int*>(adjv);
        #pragma unroll
        for (int t = 0; t < 2; ++t) {
            float s2v[8];
            *reinterpret_cast<float4*>(&s2v[0]) =
                *reinterpret_cast<const float4*>(&s2_lds[t * 32 + q * 8]);
            *reinterpret_cast<float4*>(&s2v[4]) =
                *reinterpret_cast<const float4*>(&s2_lds[t * 32 + q * 8 + 4]);
            #pragma unroll
            for (int jj = 0; jj < 8; ++jj) {
                float ev = s1v + s2v[jj];
                ev = fmaxf(ev, LRELU_ALPHA * ev);              // leaky_relu, alpha<1
                e[t * 8 + jj] = (av[t * 8 + jj] > 0) ? ev : NEG_INF;
            }
        }
        // online softmax: row max across 16 local + cross-quad
        float tmax = e[0];
        #pragma unroll
        for (int k = 1; k < 16; ++k) tmax = fmaxf(tmax, e[k]);
        tmax = fmaxf(tmax, __shfl_xor(tmax, 16));
        tmax = fmaxf(tmax, __shfl_xor(tmax, 32));
        const float m_new = fmaxf(m, tmax);
        const float alpha_s = exp2f((m - m_new) * L2E);        // exp(m - m_new)
        m = m_new;

        float tsum = 0.f;
        unsigned short pb[16];
        #pragma unroll
        for (int k = 0; k < 16; ++k) {
            float p = exp2f((e[k] - m_new) * L2E);             // exp(e - m)
            tsum += p;
            pb[k] = f2bf(p);
        }
        tsum += __shfl_xor(tsum, 16);
        tsum += __shfl_xor(tsum, 32);
        l = l * alpha_s + tsum;

        // A-fragments (already in A-layout)
        ushortx8 a0v, a1v;
        #pragma unroll
        for (int jj = 0; jj < 8; ++jj) { a0v[jj] = pb[jj]; a1v[jj] = pb[8 + jj]; }
        const bf16x8 A0 = __builtin_bit_cast(bf16x8, a0v);
        const bf16x8 A1 = __builtin_bit_cast(bf16x8, a1v);

        // rescale C by alpha of C-layout rows: row = q*4 + r, stats live at lane==row
        float ac[4];
        #pragma unroll
        for (int r = 0; r < 4; ++r) ac[r] = __shfl(alpha_s, q * 4 + r);
        #pragma unroll
        for (int u = 0; u < 4; ++u)
            #pragma unroll
            for (int r = 0; r < 4; ++r) C[u][r] *= ac[r];

        // PV: 4 f-tiles x 2 k-steps
        #pragma unroll
        for (int u = 0; u < 4; ++u) {
            const bf16x8 B0 = *reinterpret_cast<const bf16x8*>(
                &hT_lds[(u * 16 + fl) * LSTR + q * 8]);
            C[u] = __builtin_amdgcn_mfma_f32_16x16x32_bf16(A0, B0, C[u], 0, 0, 0);
            const bf16x8 B1 = *reinterpret_cast<const bf16x8*>(
                &hT_lds[(u * 16 + fl) * LSTR + 32 + q * 8]);
            C[u] = __builtin_amdgcn_mfma_f32_16x16x32_bf16(A1, B1, C[u], 0, 0, 0);
        }
        adjv[0] = nadj[0]; adjv[1] = nadj[1]; adjv[2] = nadj[2]; adjv[3] = nadj[3];
    }

    // epilogue: normalize by l (per C-row), ELU, store
    float lc[4];
    #pragma unroll
    for (int r = 0; r < 4; ++r) lc[r] = __shfl(l, q * 4 + r);
    #pragma unroll
    for (int u = 0; u < 4; ++u) {
        #pragma unroll
        for (int r = 0; r < 4; ++r) {
            float v = C[u][r] / lc[r];
            v = (v > 0.f) ? v : (exp2f(v * L2E) - 1.f);        // elu, alpha=1
            const int orow = i0 + w * 16 + q * 4 + r;
            out[((size_t)(b * Nn + orow)) * 64 + u * 16 + fl] = v;
        }
    }
}

extern "C" void kernel_launch(void* const* d_in, const int* in_sizes, int n_in,
                              void* d_out, int out_size, void* d_ws, size_t ws_size,
                              hipStream_t stream) {
    const float* x   = (const float*)d_in[0];
    const int*   adj = (const int*)d_in[1];
    const float* W   = (const float*)d_in[2];
    const float* a   = (const float*)d_in[3];
    float* out = (float*)d_out;

    // workspace: hT bf16 [B][64][N] (2 MB), then s1 [B*N], s2 [B*N] fp32
    unsigned short* hT = (unsigned short*)d_ws;
    float* s1 = (float*)((char*)d_ws + (size_t)Bb * 64 * Nn * sizeof(unsigned short));
    float* s2 = s1 + Bb * Nn;

    gat_prep<<<dim3(Bb * Nn / 64), dim3(256), 0, stream>>>(x, W, a, hT, s1, s2);
    gat_attn<<<dim3(Bb * Nn / 32), dim3(128), 0, stream>>>(adj, hT, s1, s2, out);
}

// Round 2
// 237.857 us; speedup vs baseline: 1.0347x; 1.0347x over previous
//
#include <hip/hip_runtime.h>
#include <cstdint>

#define LRELU_ALPHA 0.2f
#define NEG_INF -9000000000000000.0f
#define L2E 1.4426950408889634f

typedef __bf16 bf16x8 __attribute__((ext_vector_type(8)));
typedef unsigned short ushortx8 __attribute__((ext_vector_type(8)));
typedef float floatx4 __attribute__((ext_vector_type(4)));

constexpr int Bb = 8, Nn = 2048, Ff = 64;
constexpr int TJ = 64;            // j-tile width
constexpr int LSTR = 72;          // LDS row stride in bf16 (16B-aligned, padded vs 64)
constexpr int SEG = 8;            // j-segments (flash partial-softmax split)
constexpr int SEGT = (Nn / TJ) / SEG;   // 4 j-tiles per segment
constexpr int NROWS = Bb * Nn;    // 16384 global rows

__device__ __forceinline__ unsigned short f2bf(float f) {
    unsigned u = __builtin_bit_cast(unsigned, f);
    u = u + 0x7FFFu + ((u >> 16) & 1u);   // round-to-nearest-even
    return (unsigned short)(u >> 16);
}

// ---------------- Kernel 1: h = x@W (fp32), s1 = h.a1, s2 = h.a2, hT (bf16, transposed) ----
// grid 512 (= 2 waves/SIMD), block 256 = 4 waves; wave w owns rows il = w*8 + r.
__global__ __launch_bounds__(256) void gat_prep(
    const float* __restrict__ x, const float* __restrict__ W, const float* __restrict__ a,
    unsigned short* __restrict__ hT, float* __restrict__ s1g, float* __restrict__ s2g)
{
    constexpr int STR2 = 36;                    // [f][il] stride (bank-stride 18 -> 2-way = free)
    __shared__ unsigned short hblk[64 * STR2];
    const int tid = threadIdx.x;
    const int blk = blockIdx.x;                 // 512 blocks: 64 row-blocks x 8 batches
    const int b  = blk >> 6;
    const int i0 = (blk & 63) * 32;
    const int w    = tid >> 6;
    const int lane = tid & 63;                  // lane = output feature f

    // W column for this lane, held in VGPRs (reused across 8 rows)
    float wcol[64];
    #pragma unroll
    for (int k = 0; k < 64; ++k) wcol[k] = W[k * 64 + lane];
    const float a1 = a[lane], a2 = a[64 + lane];

    for (int r = 0; r < 8; ++r) {
        const int il = w * 8 + r;
        const int i  = i0 + il;
        const float* xrow = x + ((size_t)(b * Nn + i)) * 64;   // wave-uniform -> s_loads
        float h = 0.f;
        #pragma unroll
        for (int k = 0; k < 64; ++k) h = fmaf(xrow[k], wcol[k], h);
        float p1 = h * a1, p2 = h * a2;
        #pragma unroll
        for (int off = 32; off; off >>= 1) {
            p1 += __shfl_xor(p1, off);
            p2 += __shfl_xor(p2, off);
        }
        if (lane == 0) { s1g[b * Nn + i] = p1; s2g[b * Nn + i] = p2; }
        hblk[lane * STR2 + il] = f2bf(h);          // transpose via LDS
    }
    __syncthreads();
    // write hT[b][f][i0..i0+31]: thread t -> f = t>>2, 8-elem (16B) chunk (t&3)
    {
        const int f = tid >> 2, c = (tid & 3) * 8;
        uint4 v = *reinterpret_cast<const uint4*>(&hblk[f * STR2 + c]);
        *reinterpret_cast<uint4*>(hT + ((size_t)b * 64 + f) * Nn + i0 + c) = v;
    }
}

// ---------------- Kernel 2: fused masked-softmax attention + PV (flash-style, j-split) -----
// Block = 128 threads (2 waves), 32 rows/block, one j-segment of SEGT tiles.
// grid = SEG * 512, seg-major (consecutive blocks share hT tiles in L2).
// e-compute lane mapping == MFMA A-fragment layout: m = lane&15, k = (lane>>4)*8 + jj.
__global__ __launch_bounds__(128) void gat_attn(
    const int* __restrict__ adj, const unsigned short* __restrict__ hT,
    const float* __restrict__ s1g, const float* __restrict__ s2g,
    float* __restrict__ m_part, float* __restrict__ l_part, float* __restrict__ O_part)
{
    __shared__ unsigned short hT_lds[64 * LSTR];   // [f][j] bf16 tile, padded
    __shared__ float s2_lds[TJ];

    const int tid  = threadIdx.x;
    const int blk  = blockIdx.x;          // 4096 blocks
    const int seg  = blk >> 9;
    const int grp  = blk & 511;
    const int gr0  = grp * 32;
    const int b    = gr0 >> 11;
    const int i0   = gr0 & 2047;
    const int w    = tid >> 6;
    const int lane = tid & 63;
    const int fl   = lane & 15;           // A-row (i) in e-phase; B-col (f) in mfma phase
    const int q    = lane >> 4;           // quad id: k-group selector

    const int i = i0 + w * 16 + fl;       // this lane's score row
    const float s1v = s1g[b * Nn + i];
    const int* adj_row = adj + ((size_t)(b * Nn + i)) * Nn;
    const unsigned short* hTb = hT + (size_t)b * 64 * Nn;
    const float* s2b = s2g + b * Nn;

    float m = NEG_INF, l = 0.f;
    floatx4 C[4] = {};                    // 4 f-tiles of 16x16 C

    // staging assignment: thread -> f-row sf, 32-col chunk sc
    const int sf = tid >> 1, sc = (tid & 1) * 32;

    const int jt0 = seg * SEGT;

    // prefetch adj tile jt0 (16 ints = rows' j-window split by quad)
    int4 adjv[4];
    {
        const int* arow = adj_row + jt0 * TJ;
        const int4* ap0 = reinterpret_cast<const int4*>(arow + q * 8);
        adjv[0] = ap0[0]; adjv[1] = ap0[1];
        const int4* ap1 = reinterpret_cast<const int4*>(arow + 32 + q * 8);
        adjv[2] = ap1[0]; adjv[3] = ap1[1];
    }

    for (int jt = jt0; jt < jt0 + SEGT; ++jt) {
        const int j0 = jt * TJ;
        __syncthreads();
        // stage hT tile [64 f][64 j] -> LDS (padded), + s2 tile
        {
            const uint4* gsrc = reinterpret_cast<const uint4*>(hTb + (size_t)sf * Nn + j0 + sc);
            uint4 g0 = gsrc[0], g1 = gsrc[1], g2 = gsrc[2], g3 = gsrc[3];
            uint4* ldst = reinterpret_cast<uint4*>(&hT_lds[sf * LSTR + sc]);
            ldst[0] = g0; ldst[1] = g1; ldst[2] = g2; ldst[3] = g3;
            if (tid < TJ) s2_lds[tid] = s2b[j0 + tid];
        }
        __syncthreads();

        // prefetch next adj tile into regs (overlaps with compute below)
        int4 nadj[4] = {};
        if (jt + 1 < jt0 + SEGT) {
            const int* nrow = adj_row + j0 + TJ;
            const int4* ap0 = reinterpret_cast<const int4*>(nrow + q * 8);
            nadj[0] = ap0[0]; nadj[1] = ap0[1];
            const int4* ap1 = reinterpret_cast<const int4*>(nrow + 32 + q * 8);
            nadj[2] = ap1[0]; nadj[3] = ap1[1];
        }

        // scores: e[t*8+jj] for j = j0 + t*32 + q*8 + jj
        float e[16];
        const int* av = reinterpret_cast<const int*>(adjv);
        #pragma unroll
        for (int t = 0; t < 2; ++t) {
            float s2v[8];
            *reinterpret_cast<float4*>(&s2v[0]) =
                *reinterpret_cast<const float4*>(&s2_lds[t * 32 + q * 8]);
            *reinterpret_cast<float4*>(&s2v[4]) =
                *reinterpret_cast<const float4*>(&s2_lds[t * 32 + q * 8 + 4]);
            #pragma unroll
            for (int jj = 0; jj < 8; ++jj) {
                float ev = s1v + s2v[jj];
                ev = fmaxf(ev, LRELU_ALPHA * ev);              // leaky_relu, alpha<1
                e[t * 8 + jj] = (av[t * 8 + jj] > 0) ? ev : NEG_INF;
            }
        }
        // online softmax: row max across 16 local + cross-quad
        float tmax = e[0];
        #pragma unroll
        for (int k = 1; k < 16; ++k) tmax = fmaxf(tmax, e[k]);
        tmax = fmaxf(tmax, __shfl_xor(tmax, 16));
        tmax = fmaxf(tmax, __shfl_xor(tmax, 32));
        const float m_new = fmaxf(m, tmax);
        const float alpha_s = exp2f((m - m_new) * L2E);        // exp(m - m_new)
        m = m_new;

        float tsum = 0.f;
        float p[16];
        #pragma unroll
        for (int k = 0; k < 16; ++k) {
            p[k] = exp2f((e[k] - m_new) * L2E);                // exp(e - m)
            tsum += p[k];
        }
        tsum += __shfl_xor(tsum, 16);
        tsum += __shfl_xor(tsum, 32);
        l = l * alpha_s + tsum;

        // pack p -> bf16 A-fragments (already in A-layout)
        ushortx8 a0v, a1v;
#if __has_builtin(__builtin_amdgcn_cvt_pk_bf16_f32)
        #pragma unroll
        for (int jj = 0; jj < 4; ++jj) {
            ushortx8* dst = jj < 2 ? &a0v : &a1v;
            // fallback below covers all; packed path:
        }
        #pragma unroll
        for (int jj = 0; jj < 8; ++jj) { a0v[jj] = f2bf(p[jj]); a1v[jj] = f2bf(p[8 + jj]); }
#else
        #pragma unroll
        for (int jj = 0; jj < 8; ++jj) { a0v[jj] = f2bf(p[jj]); a1v[jj] = f2bf(p[8 + jj]); }
#endif
        const bf16x8 A0 = __builtin_bit_cast(bf16x8, a0v);
        const bf16x8 A1 = __builtin_bit_cast(bf16x8, a1v);

        // rescale C by alpha of C-layout rows: row = q*4 + r, stats live at lane (*,fl==row)
        float ac[4];
        #pragma unroll
        for (int r = 0; r < 4; ++r) ac[r] = __shfl(alpha_s, q * 4 + r);
        #pragma unroll
        for (int u = 0; u < 4; ++u)
            #pragma unroll
            for (int r = 0; r < 4; ++r) C[u][r] *= ac[r];

        // PV: 4 f-tiles x 2 k-steps
        #pragma unroll
        for (int u = 0; u < 4; ++u) {
            const bf16x8 B0 = *reinterpret_cast<const bf16x8*>(
                &hT_lds[(u * 16 + fl) * LSTR + q * 8]);
            C[u] = __builtin_amdgcn_mfma_f32_16x16x32_bf16(A0, B0, C[u], 0, 0, 0);
            const bf16x8 B1 = *reinterpret_cast<const bf16x8*>(
                &hT_lds[(u * 16 + fl) * LSTR + 32 + q * 8]);
            C[u] = __builtin_amdgcn_mfma_f32_16x16x32_bf16(A1, B1, C[u], 0, 0, 0);
        }
        adjv[0] = nadj[0]; adjv[1] = nadj[1]; adjv[2] = nadj[2]; adjv[3] = nadj[3];
    }

    // epilogue: store partial m, l, unnormalized O for this segment
    if (q == 0) {
        const int ri = b * Nn + i;        // fl-row of this wave
        m_part[seg * NROWS + ri] = m;
        l_part[seg * NROWS + ri] = l;
    }
    #pragma unroll
    for (int u = 0; u < 4; ++u) {
        #pragma unroll
        for (int r = 0; r < 4; ++r) {
            const int orow = i0 + w * 16 + q * 4 + r;
            O_part[((size_t)seg * NROWS + b * Nn + orow) * 64 + u * 16 + fl] = C[u][r];
        }
    }
}

// ---------------- Kernel 3: merge segment partials, normalize, ELU ------------------------
// grid 4096, block 256 = 4 rows/block; lane = f.
__global__ __launch_bounds__(256) void gat_merge(
    const float* __restrict__ m_part, const float* __restrict__ l_part,
    const float* __restrict__ O_part, float* __restrict__ out)
{
    const int tid = threadIdx.x;
    const int ri  = blockIdx.x * 4 + (tid >> 6);   // global row
    const int f   = tid & 63;

    float mv[SEG];
    #pragma unroll
    for (int s = 0; s < SEG; ++s) mv[s] = m_part[s * NROWS + ri];   // wave-uniform -> s_loads
    float mstar = mv[0];
    #pragma unroll
    for (int s = 1; s < SEG; ++s) mstar = fmaxf(mstar, mv[s]);

    float lsum = 0.f, acc = 0.f;
    #pragma unroll
    for (int s = 0; s < SEG; ++s) {
        const float wgt = exp2f((mv[s] - mstar) * L2E);
        lsum += l_part[s * NROWS + ri] * wgt;
        acc  += O_part[((size_t)s * NROWS + ri) * 64 + f] * wgt;
    }
    float v = acc / lsum;
    v = (v > 0.f) ? v : (exp2f(v * L2E) - 1.f);    // elu, alpha=1
    out[(size_t)ri * 64 + f] = v;
}

extern "C" void kernel_launch(void* const* d_in, const int* in_sizes, int n_in,
                              void* d_out, int out_size, void* d_ws, size_t ws_size,
                              hipStream_t stream) {
    const float* x   = (const float*)d_in[0];
    const int*   adj = (const int*)d_in[1];
    const float* W   = (const float*)d_in[2];
    const float* a   = (const float*)d_in[3];
    float* out = (float*)d_out;

    // workspace layout:
    //   hT   bf16 [B][64][N]            2 MB
    //   s1,s2 fp32 [B*N] each           128 KB
    //   m_part,l_part fp32 [SEG][B*N]   512 KB each
    //   O_part fp32 [SEG][B*N][64]      32 MB
    char* p = (char*)d_ws;
    unsigned short* hT = (unsigned short*)p;  p += (size_t)Bb * 64 * Nn * sizeof(unsigned short);
    float* s1 = (float*)p;                    p += (size_t)NROWS * sizeof(float);
    float* s2 = (float*)p;                    p += (size_t)NROWS * sizeof(float);
    float* m_part = (float*)p;                p += (size_t)SEG * NROWS * sizeof(float);
    float* l_part = (float*)p;                p += (size_t)SEG * NROWS * sizeof(float);
    float* O_part = (float*)p;

    gat_prep<<<dim3(Bb * Nn / 32), dim3(256), 0, stream>>>(x, W, a, hT, s1, s2);
    gat_attn<<<dim3(SEG * (Bb * Nn / 32)), dim3(128), 0, stream>>>(
        adj, hT, s1, s2, m_part, l_part, O_part);
    gat_merge<<<dim3(NROWS / 4), dim3(256), 0, stream>>>(m_part, l_part, O_part, out);
}